// Round 8
// baseline (115.280 us; speedup 1.0000x reference)
//
#include <hip/hip_runtime.h>
#include <cstddef>

#define NB 64
#define NL 4096
#define ND 512
#define NDP 64
#define LC 64
#define NLC (NL / LC)    // 64
#define NSLOT 4096       // wave slots in pass1 (1024 blocks x 4 waves)

typedef float v2f __attribute__((ext_vector_type(2)));

__device__ __forceinline__ v2f fma2(v2f a, v2f b, v2f c) {
    return __builtin_elementwise_fma(a, b, c);
}

// ---------------------------------------------------------------------------
// K1: partial queries (blocks 0..255) + task planner (block 256).
// ---------------------------------------------------------------------------
__global__ void __launch_bounds__(128) queries_plan_kernel(
    const float* __restrict__ source, const float* __restrict__ Wmi,
    const float* __restrict__ Wpi, const int* __restrict__ lens,
    float* __restrict__ qpm, float* __restrict__ qpp,
    int* __restrict__ table)
{
    if (blockIdx.x == NB * 4) {
        if (threadIdx.x < 64) {
            const int lane = threadIdx.x;
            const int nc = (lens[lane] + LC - 1) >> 6;   // >=1
            int pre = nc;
            #pragma unroll
            for (int off = 1; off < 64; off <<= 1) {
                const int v = __shfl_up(pre, off);
                if (lane >= off) pre += v;
            }
            const int start = pre - nc;
            for (int j = 0; j < nc; ++j) table[start + j] = (lane << 6) | j;
            const int T = __shfl(pre, 63);
            for (int s = T + lane; s < NSLOT; s += 64) table[s] = -1;
        }
        return;
    }

    __shared__ float s[128];
    const int b  = blockIdx.x >> 2;
    const int eq = blockIdx.x & 3;
    const int t  = threadIdx.x;
    const int e0 = eq * 128;
    s[t] = source[b * ND + e0 + t];
    __syncthreads();

    const int d0 = t * 4;
    float4 a0 = {0,0,0,0}, a1 = {0,0,0,0};
    #pragma unroll 4
    for (int e = 0; e < 128; e += 2) {
        const float4 w0 = *(const float4*)(Wmi + (size_t)(e0 + e) * ND + d0);
        const float4 w1 = *(const float4*)(Wmi + (size_t)(e0 + e + 1) * ND + d0);
        const float x0 = s[e], x1 = s[e + 1];
        a0.x = fmaf(x0, w0.x, a0.x); a0.y = fmaf(x0, w0.y, a0.y);
        a0.z = fmaf(x0, w0.z, a0.z); a0.w = fmaf(x0, w0.w, a0.w);
        a1.x = fmaf(x1, w1.x, a1.x); a1.y = fmaf(x1, w1.y, a1.y);
        a1.z = fmaf(x1, w1.z, a1.z); a1.w = fmaf(x1, w1.w, a1.w);
    }
    a0.x += a1.x; a0.y += a1.y; a0.z += a1.z; a0.w += a1.w;
    *(float4*)(qpm + (size_t)(b * 4 + eq) * ND + d0) = a0;

    if (t < NDP) {
        float c0 = 0.f, c1 = 0.f;
        #pragma unroll 4
        for (int e = 0; e < 128; e += 2) {
            c0 = fmaf(s[e],     Wpi[(size_t)(e0 + e) * NDP + t],     c0);
            c1 = fmaf(s[e + 1], Wpi[(size_t)(e0 + e + 1) * NDP + t], c1);
        }
        qpp[(b * 4 + eq) * NDP + t] = c0 + c1;
    }
}

// ---------------------------------------------------------------------------
// K2: fused scorer, table-driven, copy-free ping-pong 4-row groups.
// While group A is processed, group B's 4 rows (9 KB/wave) are in flight:
// counted vmcnt waits, no register shifts, no per-row drains.
// ---------------------------------------------------------------------------
__global__ void __launch_bounds__(256, 4) pass1_kernel(
    const float* __restrict__ me, const float* __restrict__ pe,
    const float* __restrict__ qpm, const float* __restrict__ qpp,
    const int* __restrict__ mem_len, const int* __restrict__ table,
    float* __restrict__ a_main, float* __restrict__ a_pos,
    float* __restrict__ Sbuf, float* __restrict__ MZ)
{
    __shared__ __align__(16) float qp_lds[4][NDP];
    const int lane = threadIdx.x & 63;
    const int wid  = threadIdx.x >> 6;
    const int task = table[blockIdx.x * 4 + wid];
    if (task < 0) return;
    const int b  = task >> 6;
    const int lc = task & 63;

    const int len  = mem_len[b];
    const int l0   = lc * LC;
    const int nrow = min(LC, len - l0);
    const int nr4  = (nrow + 3) & ~3;
    const int last = nrow - 1;

    // query fragments (lane-distributed) + qp into LDS
    float4 q0 = {0,0,0,0}, q1 = {0,0,0,0};
    float qp = 0.f;
    #pragma unroll
    for (int eq = 0; eq < 4; ++eq) {
        const float4* qr = (const float4*)(qpm + (size_t)(b * 4 + eq) * ND);
        const float4 u0 = qr[lane], u1 = qr[64 + lane];
        q0.x += u0.x; q0.y += u0.y; q0.z += u0.z; q0.w += u0.w;
        q1.x += u1.x; q1.y += u1.y; q1.z += u1.z; q1.w += u1.w;
        qp += qpp[(b * 4 + eq) * NDP + lane];
    }
    qp_lds[wid][lane] = qp;

    // pe: lane j computes the full 64-dot for row l0+(j&31)
    float accp = 0.f;
    {
        const int prow = l0 + (lane & 31) ? l0 + (lane & 63) : l0;  // see below
    }
    // (lane handles row l0+lane when lane < nrow; others clamp harmlessly)
    {
        const int prow = l0 + min(lane, last);
        const float4* pr = (const float4*)(pe + ((size_t)prow * NB + b) * NDP);
        #pragma unroll
        for (int k = 0; k < 16; ++k) {
            const float4 pv = pr[k];
            const float4 qv = *(const float4*)&qp_lds[wid][k * 4];
            accp = fmaf(pv.x, qv.x, accp);
            accp = fmaf(pv.y, qv.y, accp);
            accp = fmaf(pv.z, qv.z, accp);
            accp = fmaf(pv.w, qv.w, accp);
        }
        if (lane < nrow) a_pos[(size_t)b * NL + l0 + lane] = accp;
    }
    const int accp_i = __float_as_int(accp);

    const size_t rstride = (size_t)NB * ND;
    const float* base = me + ((size_t)l0 * NB + b) * ND;

    float m = -1e30f, Z = 0.f, keep = 0.f;
    v2f S0 = {0,0}, S1 = {0,0}, S2 = {0,0}, S3 = {0,0};

    float4 A[4][2], B[4][2];

    // process one 4-row group (fully unrolled; interleaved butterflies)
    auto process = [&](float4 R[4][2], int i0) {
        float acc[4];
        #pragma unroll
        for (int j = 0; j < 4; ++j) {
            v2f dd = {0.f, 0.f};
            dd = fma2((v2f){R[j][0].x, R[j][0].y}, (v2f){q0.x, q0.y}, dd);
            dd = fma2((v2f){R[j][0].z, R[j][0].w}, (v2f){q0.z, q0.w}, dd);
            dd = fma2((v2f){R[j][1].x, R[j][1].y}, (v2f){q1.x, q1.y}, dd);
            dd = fma2((v2f){R[j][1].z, R[j][1].w}, (v2f){q1.z, q1.w}, dd);
            acc[j] = dd.x + dd.y;
        }
        #pragma unroll
        for (int off = 32; off; off >>= 1) {
            #pragma unroll
            for (int j = 0; j < 4; ++j)
                acc[j] += __shfl_xor(acc[j], off);
        }
        #pragma unroll
        for (int j = 0; j < 4; ++j) {
            const int row = i0 + j;
            keep = (lane == row) ? acc[j] : keep;
            const float ap = __int_as_float(
                __builtin_amdgcn_readlane(accp_i, min(row, last)));
            const float sv = (row < nrow) ? acc[j] + ap : -1e30f;
            if (sv > m) {                 // wave-uniform; new-max path w = 1
                const float sc = __expf(m - sv);
                const v2f sc2 = {sc, sc};
                Z = fmaf(Z, sc, 1.f);
                S0 = fma2(S0, sc2, (v2f){R[j][0].x, R[j][0].y});
                S1 = fma2(S1, sc2, (v2f){R[j][0].z, R[j][0].w});
                S2 = fma2(S2, sc2, (v2f){R[j][1].x, R[j][1].y});
                S3 = fma2(S3, sc2, (v2f){R[j][1].z, R[j][1].w});
                m = sv;
            } else {
                const float w = __expf(sv - m);
                const v2f w2 = {w, w};
                Z += w;
                S0 = fma2((v2f){R[j][0].x, R[j][0].y}, w2, S0);
                S1 = fma2((v2f){R[j][0].z, R[j][0].w}, w2, S1);
                S2 = fma2((v2f){R[j][1].x, R[j][1].y}, w2, S2);
                S3 = fma2((v2f){R[j][1].z, R[j][1].w}, w2, S3);
            }
        }
    };

    // prologue: A = rows 0..3 (clamped)
    #pragma unroll
    for (int j = 0; j < 4; ++j) {
        const float* p = base + (size_t)min(j, last) * rstride;
        A[j][0] = ((const float4*)p)[lane];
        A[j][1] = ((const float4*)p)[64 + lane];
    }

    int i = 0;
    for (;;) {
        #pragma unroll
        for (int j = 0; j < 4; ++j) {
            const float* p = base + (size_t)min(i + 4 + j, last) * rstride;
            B[j][0] = ((const float4*)p)[lane];
            B[j][1] = ((const float4*)p)[64 + lane];
        }
        process(A, i);
        i += 4;
        if (i >= nr4) break;

        #pragma unroll
        for (int j = 0; j < 4; ++j) {
            const float* p = base + (size_t)min(i + 4 + j, last) * rstride;
            A[j][0] = ((const float4*)p)[lane];
            A[j][1] = ((const float4*)p)[64 + lane];
        }
        process(B, i);
        i += 4;
        if (i >= nr4) break;
    }

    if (lane < nrow) a_main[(size_t)b * NL + l0 + lane] = keep;

    float* sp = Sbuf + ((size_t)b * NLC + lc) * ND;
    ((float4*)sp)[lane]      = (float4){S0.x, S0.y, S1.x, S1.y};
    ((float4*)sp)[64 + lane] = (float4){S2.x, S2.y, S3.x, S3.y};
    if (lane == 0) {
        MZ[2 * (b * NLC + lc)]     = m;
        MZ[2 * (b * NLC + lc) + 1] = Z;
    }
}

// ---------------------------------------------------------------------------
// K3 (merged): per-b stats + finalize + context sum. coef kept in LDS.
// ---------------------------------------------------------------------------
__global__ void __launch_bounds__(1024) stats_ctx_kernel(
    const float* __restrict__ MZ, const float* __restrict__ Sbuf,
    const int* __restrict__ mem_len,
    float* __restrict__ ma_io, float* __restrict__ pa_io,
    float* __restrict__ out_av, float* __restrict__ c_t)
{
    __shared__ float red[16][6];
    __shared__ float bc[6];
    __shared__ float coef_s[NLC];
    const int b = blockIdx.x;
    const int tid = threadIdx.x;
    const int lane = tid & 63, wid = tid >> 6;
    const int len = mem_len[b];

    float va[4], vp[4];
    float Am = -1e30f, Pm = -1e30f, Cm = -1e30f;
    #pragma unroll
    for (int k = 0; k < 4; ++k) {
        const int l = tid + k * 1024;
        va[k] = ma_io[(size_t)b * NL + l];
        vp[k] = pa_io[(size_t)b * NL + l];
        if (l < len) {
            Am = fmaxf(Am, va[k]);
            Pm = fmaxf(Pm, vp[k]);
            Cm = fmaxf(Cm, va[k] + vp[k]);
        }
    }
    #pragma unroll
    for (int off = 32; off; off >>= 1) {
        Am = fmaxf(Am, __shfl_xor(Am, off));
        Pm = fmaxf(Pm, __shfl_xor(Pm, off));
        Cm = fmaxf(Cm, __shfl_xor(Cm, off));
    }
    if (lane == 0) { red[wid][0] = Am; red[wid][1] = Pm; red[wid][2] = Cm; }
    __syncthreads();
    if (tid < 16) {
        float a = red[tid][0], p = red[tid][1], c = red[tid][2];
        #pragma unroll
        for (int off = 8; off; off >>= 1) {
            a = fmaxf(a, __shfl_xor(a, off));
            p = fmaxf(p, __shfl_xor(p, off));
            c = fmaxf(c, __shfl_xor(c, off));
        }
        if (tid == 0) { bc[0] = a; bc[1] = p; bc[2] = c; }
    }
    __syncthreads();
    const float MA = bc[0], MP = bc[1], MC = bc[2];

    float Az = 0.f, Pz = 0.f, Cz = 0.f;
    #pragma unroll
    for (int k = 0; k < 4; ++k) {
        const int l = tid + k * 1024;
        if (l < len) {
            Az += __expf(va[k] - MA);
            Pz += __expf(vp[k] - MP);
            Cz += __expf(va[k] + vp[k] - MC);
        }
    }
    #pragma unroll
    for (int off = 32; off; off >>= 1) {
        Az += __shfl_xor(Az, off);
        Pz += __shfl_xor(Pz, off);
        Cz += __shfl_xor(Cz, off);
    }
    if (lane == 0) { red[wid][3] = Az; red[wid][4] = Pz; red[wid][5] = Cz; }
    __syncthreads();
    if (tid < 16) {
        float a = red[tid][3], p = red[tid][4], c = red[tid][5];
        #pragma unroll
        for (int off = 8; off; off >>= 1) {
            a += __shfl_xor(a, off);
            p += __shfl_xor(p, off);
            c += __shfl_xor(c, off);
        }
        if (tid == 0) { bc[3] = a; bc[4] = p; bc[5] = c; }
    }
    __syncthreads();
    const float iA = 1.f / bc[3], iP = 1.f / bc[4], iC = 1.f / bc[5];
    const int nv = (len + LC - 1) >> 6;

    if (tid < NLC) {
        const float mlc = MZ[2 * (b * NLC + tid)];
        coef_s[tid] = (tid < nv) ? __expf(mlc - MC) * iC : 0.f;
    }

    #pragma unroll
    for (int k = 0; k < 4; ++k) {
        const int l = tid + k * 1024;
        const bool v = l < len;
        const size_t idx = (size_t)b * NL + l;
        ma_io[idx]  = v ? __expf(va[k] - MA) * iA : 0.f;
        pa_io[idx]  = v ? __expf(vp[k] - MP) * iP : 0.f;
        out_av[idx] = v ? __expf(va[k] + vp[k] - MC) * iC : 0.f;
    }
    __syncthreads();

    // context sum: 128 threads x float4 over valid chunks
    if (tid < 128) {
        float4 acc = {0.f, 0.f, 0.f, 0.f};
        for (int lcc = 0; lcc < nv; ++lcc) {
            const float cf = coef_s[lcc];
            const float4 sv4 =
                ((const float4*)(Sbuf + ((size_t)b * NLC + lcc) * ND))[tid];
            acc.x = fmaf(cf, sv4.x, acc.x);
            acc.y = fmaf(cf, sv4.y, acc.y);
            acc.z = fmaf(cf, sv4.z, acc.z);
            acc.w = fmaf(cf, sv4.w, acc.w);
        }
        ((float4*)(c_t + b * ND))[tid] = acc;
    }
}

// ---------------------------------------------------------------------------
// K4: attn_h[b,e] = tanh(<[c_t, source], W_out[e,:]>)
// ---------------------------------------------------------------------------
__global__ void __launch_bounds__(256) out_kernel(
    const float* __restrict__ c_t, const float* __restrict__ source,
    const float* __restrict__ Wout, float* __restrict__ attn_h)
{
    __shared__ float cs[2 * ND];
    const int b = blockIdx.x >> 3;
    const int eg = blockIdx.x & 7;
    const int tid = threadIdx.x;

    for (int d = tid; d < ND; d += 256) {
        cs[d] = c_t[b * ND + d];
        cs[ND + d] = source[b * ND + d];
    }
    __syncthreads();

    const int wid = tid >> 6, lane = tid & 63;
    const float4* csv = (const float4*)cs;
    for (int e = eg * 64 + wid; e < eg * 64 + 64; e += 4) {
        const float4* wrow = (const float4*)(Wout + (size_t)e * 2 * ND);
        float acc = 0.f;
        #pragma unroll
        for (int j = 0; j < 4; ++j) {
            const float4 w = wrow[lane + 64 * j];
            const float4 c = csv[lane + 64 * j];
            acc += w.x * c.x + w.y * c.y + w.z * c.z + w.w * c.w;
        }
        #pragma unroll
        for (int off = 32; off; off >>= 1) acc += __shfl_xor(acc, off);
        if (lane == 0) attn_h[(size_t)b * ND + e] = tanhf(acc);
    }
}

// ---------------------------------------------------------------------------
extern "C" void kernel_launch(void* const* d_in, const int* in_sizes, int n_in,
                              void* d_out, int out_size, void* d_ws, size_t ws_size,
                              hipStream_t stream)
{
    const float* source = (const float*)d_in[0];
    const float* me     = (const float*)d_in[1];   // (L, B, D)
    const float* pe     = (const float*)d_in[2];   // (L, B, DP)
    const float* Wmi    = (const float*)d_in[3];   // (D, D)
    const float* Wpi    = (const float*)d_in[4];   // (D, DP)
    const float* Wout   = (const float*)d_in[5];   // (D, 2D)
    const int*   lens   = (const int*)d_in[6];     // (B,)

    float* out    = (float*)d_out;
    float* attn_h = out;                     // (B, D)
    float* av     = attn_h + NB * ND;        // (B, L)
    float* ma     = av + NB * NL;            // (B, L) raw a_main -> in-place
    float* pa     = ma + NB * NL;            // (B, L) raw a_pos  -> in-place

    float* ws    = (float*)d_ws;
    float* qpm   = ws;                              // NB*4*ND
    float* qpp   = qpm + NB * 4 * ND;               // NB*4*NDP
    float* Sbuf  = qpp + NB * 4 * NDP;              // NB*NLC*ND
    float* MZ    = Sbuf + (size_t)NB * NLC * ND;    // NB*NLC*2
    float* c_t   = MZ + NB * NLC * 2;               // NB*ND
    int*   table = (int*)(c_t + NB * ND);           // NSLOT ints

    queries_plan_kernel<<<NB * 4 + 1, 128, 0, stream>>>(source, Wmi, Wpi,
                                                        lens, qpm, qpp, table);
    pass1_kernel       <<<NSLOT / 4, 256, 0, stream>>>(me, pe, qpm, qpp, lens,
                                                       table, ma, pa, Sbuf, MZ);
    stats_ctx_kernel   <<<NB, 1024, 0, stream>>>(MZ, Sbuf, lens, ma, pa, av, c_t);
    out_kernel         <<<NB * 8, 256, 0, stream>>>(c_t, source, Wout, attn_h);
}

// Round 9
// 115.176 us; speedup vs baseline: 1.0009x; 1.0009x over previous
//
#include <hip/hip_runtime.h>
#include <cstddef>

#define NB 64
#define NL 4096
#define ND 512
#define NDP 64
#define LC 64
#define NLC (NL / LC)    // 64
#define NSLOT 4096       // wave slots in pass1 (1024 blocks x 4 waves)

typedef float v2f __attribute__((ext_vector_type(2)));

__device__ __forceinline__ v2f fma2(v2f a, v2f b, v2f c) {
    return __builtin_elementwise_fma(a, b, c);
}

// ---------------------------------------------------------------------------
// K1: partial queries (blocks 0..255) + task planner (block 256).
// ---------------------------------------------------------------------------
__global__ void __launch_bounds__(128) queries_plan_kernel(
    const float* __restrict__ source, const float* __restrict__ Wmi,
    const float* __restrict__ Wpi, const int* __restrict__ lens,
    float* __restrict__ qpm, float* __restrict__ qpp,
    int* __restrict__ table)
{
    if (blockIdx.x == NB * 4) {
        if (threadIdx.x < 64) {
            const int lane = threadIdx.x;
            const int nc = (lens[lane] + LC - 1) >> 6;   // >=1
            int pre = nc;
            #pragma unroll
            for (int off = 1; off < 64; off <<= 1) {
                const int v = __shfl_up(pre, off);
                if (lane >= off) pre += v;
            }
            const int start = pre - nc;
            for (int j = 0; j < nc; ++j) table[start + j] = (lane << 6) | j;
            const int T = __shfl(pre, 63);
            for (int s = T + lane; s < NSLOT; s += 64) table[s] = -1;
        }
        return;
    }

    __shared__ float s[128];
    const int b  = blockIdx.x >> 2;
    const int eq = blockIdx.x & 3;
    const int t  = threadIdx.x;
    const int e0 = eq * 128;
    s[t] = source[b * ND + e0 + t];
    __syncthreads();

    const int d0 = t * 4;
    float4 a0 = {0,0,0,0}, a1 = {0,0,0,0};
    #pragma unroll 4
    for (int e = 0; e < 128; e += 2) {
        const float4 w0 = *(const float4*)(Wmi + (size_t)(e0 + e) * ND + d0);
        const float4 w1 = *(const float4*)(Wmi + (size_t)(e0 + e + 1) * ND + d0);
        const float x0 = s[e], x1 = s[e + 1];
        a0.x = fmaf(x0, w0.x, a0.x); a0.y = fmaf(x0, w0.y, a0.y);
        a0.z = fmaf(x0, w0.z, a0.z); a0.w = fmaf(x0, w0.w, a0.w);
        a1.x = fmaf(x1, w1.x, a1.x); a1.y = fmaf(x1, w1.y, a1.y);
        a1.z = fmaf(x1, w1.z, a1.z); a1.w = fmaf(x1, w1.w, a1.w);
    }
    a0.x += a1.x; a0.y += a1.y; a0.z += a1.z; a0.w += a1.w;
    *(float4*)(qpm + (size_t)(b * 4 + eq) * ND + d0) = a0;

    if (t < NDP) {
        float c0 = 0.f, c1 = 0.f;
        #pragma unroll 4
        for (int e = 0; e < 128; e += 2) {
            c0 = fmaf(s[e],     Wpi[(size_t)(e0 + e) * NDP + t],     c0);
            c1 = fmaf(s[e + 1], Wpi[(size_t)(e0 + e + 1) * NDP + t], c1);
        }
        qpp[(b * 4 + eq) * NDP + t] = c0 + c1;
    }
}

// ---------------------------------------------------------------------------
// K2: fused scorer, table-driven, copy-free ping-pong 4-row groups.
// While group A is processed, group B's 4 rows (9 KB/wave) are in flight:
// counted vmcnt waits, no register shifts, no per-row drains.
// ---------------------------------------------------------------------------
__global__ void __launch_bounds__(256, 4) pass1_kernel(
    const float* __restrict__ me, const float* __restrict__ pe,
    const float* __restrict__ qpm, const float* __restrict__ qpp,
    const int* __restrict__ mem_len, const int* __restrict__ table,
    float* __restrict__ a_main, float* __restrict__ a_pos,
    float* __restrict__ Sbuf, float* __restrict__ MZ)
{
    __shared__ __align__(16) float qp_lds[4][NDP];
    const int lane = threadIdx.x & 63;
    const int wid  = threadIdx.x >> 6;
    const int task = table[blockIdx.x * 4 + wid];
    if (task < 0) return;
    const int b  = task >> 6;
    const int lc = task & 63;

    const int len  = mem_len[b];
    const int l0   = lc * LC;
    const int nrow = min(LC, len - l0);
    const int nr4  = (nrow + 3) & ~3;
    const int last = nrow - 1;

    // query fragments (lane-distributed) + qp into LDS
    float4 q0 = {0,0,0,0}, q1 = {0,0,0,0};
    float qp = 0.f;
    #pragma unroll
    for (int eq = 0; eq < 4; ++eq) {
        const float4* qr = (const float4*)(qpm + (size_t)(b * 4 + eq) * ND);
        const float4 u0 = qr[lane], u1 = qr[64 + lane];
        q0.x += u0.x; q0.y += u0.y; q0.z += u0.z; q0.w += u0.w;
        q1.x += u1.x; q1.y += u1.y; q1.z += u1.z; q1.w += u1.w;
        qp += qpp[(b * 4 + eq) * NDP + lane];
    }
    qp_lds[wid][lane] = qp;

    // pe: lane j computes the full 64-dot for row l0+(j&31)
    float accp = 0.f;
    {
        const int prow = l0 + (lane & 31) ? l0 + (lane & 63) : l0;  // see below
    }
    // (lane handles row l0+lane when lane < nrow; others clamp harmlessly)
    {
        const int prow = l0 + min(lane, last);
        const float4* pr = (const float4*)(pe + ((size_t)prow * NB + b) * NDP);
        #pragma unroll
        for (int k = 0; k < 16; ++k) {
            const float4 pv = pr[k];
            const float4 qv = *(const float4*)&qp_lds[wid][k * 4];
            accp = fmaf(pv.x, qv.x, accp);
            accp = fmaf(pv.y, qv.y, accp);
            accp = fmaf(pv.z, qv.z, accp);
            accp = fmaf(pv.w, qv.w, accp);
        }
        if (lane < nrow) a_pos[(size_t)b * NL + l0 + lane] = accp;
    }
    const int accp_i = __float_as_int(accp);

    const size_t rstride = (size_t)NB * ND;
    const float* base = me + ((size_t)l0 * NB + b) * ND;

    float m = -1e30f, Z = 0.f, keep = 0.f;
    v2f S0 = {0,0}, S1 = {0,0}, S2 = {0,0}, S3 = {0,0};

    float4 A[4][2], B[4][2];

    // process one 4-row group (fully unrolled; interleaved butterflies)
    auto process = [&](float4 R[4][2], int i0) {
        float acc[4];
        #pragma unroll
        for (int j = 0; j < 4; ++j) {
            v2f dd = {0.f, 0.f};
            dd = fma2((v2f){R[j][0].x, R[j][0].y}, (v2f){q0.x, q0.y}, dd);
            dd = fma2((v2f){R[j][0].z, R[j][0].w}, (v2f){q0.z, q0.w}, dd);
            dd = fma2((v2f){R[j][1].x, R[j][1].y}, (v2f){q1.x, q1.y}, dd);
            dd = fma2((v2f){R[j][1].z, R[j][1].w}, (v2f){q1.z, q1.w}, dd);
            acc[j] = dd.x + dd.y;
        }
        #pragma unroll
        for (int off = 32; off; off >>= 1) {
            #pragma unroll
            for (int j = 0; j < 4; ++j)
                acc[j] += __shfl_xor(acc[j], off);
        }
        #pragma unroll
        for (int j = 0; j < 4; ++j) {
            const int row = i0 + j;
            keep = (lane == row) ? acc[j] : keep;
            const float ap = __int_as_float(
                __builtin_amdgcn_readlane(accp_i, min(row, last)));
            const float sv = (row < nrow) ? acc[j] + ap : -1e30f;
            if (sv > m) {                 // wave-uniform; new-max path w = 1
                const float sc = __expf(m - sv);
                const v2f sc2 = {sc, sc};
                Z = fmaf(Z, sc, 1.f);
                S0 = fma2(S0, sc2, (v2f){R[j][0].x, R[j][0].y});
                S1 = fma2(S1, sc2, (v2f){R[j][0].z, R[j][0].w});
                S2 = fma2(S2, sc2, (v2f){R[j][1].x, R[j][1].y});
                S3 = fma2(S3, sc2, (v2f){R[j][1].z, R[j][1].w});
                m = sv;
            } else {
                const float w = __expf(sv - m);
                const v2f w2 = {w, w};
                Z += w;
                S0 = fma2((v2f){R[j][0].x, R[j][0].y}, w2, S0);
                S1 = fma2((v2f){R[j][0].z, R[j][0].w}, w2, S1);
                S2 = fma2((v2f){R[j][1].x, R[j][1].y}, w2, S2);
                S3 = fma2((v2f){R[j][1].z, R[j][1].w}, w2, S3);
            }
        }
    };

    // prologue: A = rows 0..3 (clamped)
    #pragma unroll
    for (int j = 0; j < 4; ++j) {
        const float* p = base + (size_t)min(j, last) * rstride;
        A[j][0] = ((const float4*)p)[lane];
        A[j][1] = ((const float4*)p)[64 + lane];
    }

    int i = 0;
    for (;;) {
        #pragma unroll
        for (int j = 0; j < 4; ++j) {
            const float* p = base + (size_t)min(i + 4 + j, last) * rstride;
            B[j][0] = ((const float4*)p)[lane];
            B[j][1] = ((const float4*)p)[64 + lane];
        }
        process(A, i);
        i += 4;
        if (i >= nr4) break;

        #pragma unroll
        for (int j = 0; j < 4; ++j) {
            const float* p = base + (size_t)min(i + 4 + j, last) * rstride;
            A[j][0] = ((const float4*)p)[lane];
            A[j][1] = ((const float4*)p)[64 + lane];
        }
        process(B, i);
        i += 4;
        if (i >= nr4) break;
    }

    if (lane < nrow) a_main[(size_t)b * NL + l0 + lane] = keep;

    float* sp = Sbuf + ((size_t)b * NLC + lc) * ND;
    ((float4*)sp)[lane]      = (float4){S0.x, S0.y, S1.x, S1.y};
    ((float4*)sp)[64 + lane] = (float4){S2.x, S2.y, S3.x, S3.y};
    if (lane == 0) {
        MZ[2 * (b * NLC + lc)]     = m;
        MZ[2 * (b * NLC + lc) + 1] = Z;
    }
}

// ---------------------------------------------------------------------------
// K3 (merged): per-b stats + finalize + context sum. coef kept in LDS.
// ---------------------------------------------------------------------------
__global__ void __launch_bounds__(1024) stats_ctx_kernel(
    const float* __restrict__ MZ, const float* __restrict__ Sbuf,
    const int* __restrict__ mem_len,
    float* __restrict__ ma_io, float* __restrict__ pa_io,
    float* __restrict__ out_av, float* __restrict__ c_t)
{
    __shared__ float red[16][6];
    __shared__ float bc[6];
    __shared__ float coef_s[NLC];
    const int b = blockIdx.x;
    const int tid = threadIdx.x;
    const int lane = tid & 63, wid = tid >> 6;
    const int len = mem_len[b];

    float va[4], vp[4];
    float Am = -1e30f, Pm = -1e30f, Cm = -1e30f;
    #pragma unroll
    for (int k = 0; k < 4; ++k) {
        const int l = tid + k * 1024;
        va[k] = ma_io[(size_t)b * NL + l];
        vp[k] = pa_io[(size_t)b * NL + l];
        if (l < len) {
            Am = fmaxf(Am, va[k]);
            Pm = fmaxf(Pm, vp[k]);
            Cm = fmaxf(Cm, va[k] + vp[k]);
        }
    }
    #pragma unroll
    for (int off = 32; off; off >>= 1) {
        Am = fmaxf(Am, __shfl_xor(Am, off));
        Pm = fmaxf(Pm, __shfl_xor(Pm, off));
        Cm = fmaxf(Cm, __shfl_xor(Cm, off));
    }
    if (lane == 0) { red[wid][0] = Am; red[wid][1] = Pm; red[wid][2] = Cm; }
    __syncthreads();
    if (tid < 16) {
        float a = red[tid][0], p = red[tid][1], c = red[tid][2];
        #pragma unroll
        for (int off = 8; off; off >>= 1) {
            a = fmaxf(a, __shfl_xor(a, off));
            p = fmaxf(p, __shfl_xor(p, off));
            c = fmaxf(c, __shfl_xor(c, off));
        }
        if (tid == 0) { bc[0] = a; bc[1] = p; bc[2] = c; }
    }
    __syncthreads();
    const float MA = bc[0], MP = bc[1], MC = bc[2];

    float Az = 0.f, Pz = 0.f, Cz = 0.f;
    #pragma unroll
    for (int k = 0; k < 4; ++k) {
        const int l = tid + k * 1024;
        if (l < len) {
            Az += __expf(va[k] - MA);
            Pz += __expf(vp[k] - MP);
            Cz += __expf(va[k] + vp[k] - MC);
        }
    }
    #pragma unroll
    for (int off = 32; off; off >>= 1) {
        Az += __shfl_xor(Az, off);
        Pz += __shfl_xor(Pz, off);
        Cz += __shfl_xor(Cz, off);
    }
    if (lane == 0) { red[wid][3] = Az; red[wid][4] = Pz; red[wid][5] = Cz; }
    __syncthreads();
    if (tid < 16) {
        float a = red[tid][3], p = red[tid][4], c = red[tid][5];
        #pragma unroll
        for (int off = 8; off; off >>= 1) {
            a += __shfl_xor(a, off);
            p += __shfl_xor(p, off);
            c += __shfl_xor(c, off);
        }
        if (tid == 0) { bc[3] = a; bc[4] = p; bc[5] = c; }
    }
    __syncthreads();
    const float iA = 1.f / bc[3], iP = 1.f / bc[4], iC = 1.f / bc[5];
    const int nv = (len + LC - 1) >> 6;

    if (tid < NLC) {
        const float mlc = MZ[2 * (b * NLC + tid)];
        coef_s[tid] = (tid < nv) ? __expf(mlc - MC) * iC : 0.f;
    }

    #pragma unroll
    for (int k = 0; k < 4; ++k) {
        const int l = tid + k * 1024;
        const bool v = l < len;
        const size_t idx = (size_t)b * NL + l;
        ma_io[idx]  = v ? __expf(va[k] - MA) * iA : 0.f;
        pa_io[idx]  = v ? __expf(vp[k] - MP) * iP : 0.f;
        out_av[idx] = v ? __expf(va[k] + vp[k] - MC) * iC : 0.f;
    }
    __syncthreads();

    // context sum: 128 threads x float4 over valid chunks
    if (tid < 128) {
        float4 acc = {0.f, 0.f, 0.f, 0.f};
        for (int lcc = 0; lcc < nv; ++lcc) {
            const float cf = coef_s[lcc];
            const float4 sv4 =
                ((const float4*)(Sbuf + ((size_t)b * NLC + lcc) * ND))[tid];
            acc.x = fmaf(cf, sv4.x, acc.x);
            acc.y = fmaf(cf, sv4.y, acc.y);
            acc.z = fmaf(cf, sv4.z, acc.z);
            acc.w = fmaf(cf, sv4.w, acc.w);
        }
        ((float4*)(c_t + b * ND))[tid] = acc;
    }
}

// ---------------------------------------------------------------------------
// K4: attn_h[b,e] = tanh(<[c_t, source], W_out[e,:]>)
// ---------------------------------------------------------------------------
__global__ void __launch_bounds__(256) out_kernel(
    const float* __restrict__ c_t, const float* __restrict__ source,
    const float* __restrict__ Wout, float* __restrict__ attn_h)
{
    __shared__ float cs[2 * ND];
    const int b = blockIdx.x >> 3;
    const int eg = blockIdx.x & 7;
    const int tid = threadIdx.x;

    for (int d = tid; d < ND; d += 256) {
        cs[d] = c_t[b * ND + d];
        cs[ND + d] = source[b * ND + d];
    }
    __syncthreads();

    const int wid = tid >> 6, lane = tid & 63;
    const float4* csv = (const float4*)cs;
    for (int e = eg * 64 + wid; e < eg * 64 + 64; e += 4) {
        const float4* wrow = (const float4*)(Wout + (size_t)e * 2 * ND);
        float acc = 0.f;
        #pragma unroll
        for (int j = 0; j < 4; ++j) {
            const float4 w = wrow[lane + 64 * j];
            const float4 c = csv[lane + 64 * j];
            acc += w.x * c.x + w.y * c.y + w.z * c.z + w.w * c.w;
        }
        #pragma unroll
        for (int off = 32; off; off >>= 1) acc += __shfl_xor(acc, off);
        if (lane == 0) attn_h[(size_t)b * ND + e] = tanhf(acc);
    }
}

// ---------------------------------------------------------------------------
extern "C" void kernel_launch(void* const* d_in, const int* in_sizes, int n_in,
                              void* d_out, int out_size, void* d_ws, size_t ws_size,
                              hipStream_t stream)
{
    const float* source = (const float*)d_in[0];
    const float* me     = (const float*)d_in[1];   // (L, B, D)
    const float* pe     = (const float*)d_in[2];   // (L, B, DP)
    const float* Wmi    = (const float*)d_in[3];   // (D, D)
    const float* Wpi    = (const float*)d_in[4];   // (D, DP)
    const float* Wout   = (const float*)d_in[5];   // (D, 2D)
    const int*   lens   = (const int*)d_in[6];     // (B,)

    float* out    = (float*)d_out;
    float* attn_h = out;                     // (B, D)
    float* av     = attn_h + NB * ND;        // (B, L)
    float* ma     = av + NB * NL;            // (B, L) raw a_main -> in-place
    float* pa     = ma + NB * NL;            // (B, L) raw a_pos  -> in-place

    float* ws    = (float*)d_ws;
    float* qpm   = ws;                              // NB*4*ND
    float* qpp   = qpm + NB * 4 * ND;               // NB*4*NDP
    float* Sbuf  = qpp + NB * 4 * NDP;              // NB*NLC*ND
    float* MZ    = Sbuf + (size_t)NB * NLC * ND;    // NB*NLC*2
    float* c_t   = MZ + NB * NLC * 2;               // NB*ND
    int*   table = (int*)(c_t + NB * ND);           // NSLOT ints

    queries_plan_kernel<<<NB * 4 + 1, 128, 0, stream>>>(source, Wmi, Wpi,
                                                        lens, qpm, qpp, table);
    pass1_kernel       <<<NSLOT / 4, 256, 0, stream>>>(me, pe, qpm, qpp, lens,
                                                       table, ma, pa, Sbuf, MZ);
    stats_ctx_kernel   <<<NB, 1024, 0, stream>>>(MZ, Sbuf, lens, ma, pa, av, c_t);
    out_kernel         <<<NB * 8, 256, 0, stream>>>(c_t, source, Wout, attn_h);
}

// Round 10
// 115.161 us; speedup vs baseline: 1.0010x; 1.0001x over previous
//
#include <hip/hip_runtime.h>
#include <cstddef>

#define NB 64
#define NL 4096
#define ND 512
#define NDP 64
#define LC 64
#define NLC (NL / LC)    // 64
#define NSLOT 4096       // wave slots in pass1 (1024 blocks x 4 waves)

typedef float v2f __attribute__((ext_vector_type(2)));

__device__ __forceinline__ v2f fma2(v2f a, v2f b, v2f c) {
    return __builtin_elementwise_fma(a, b, c);
}

// ---------------------------------------------------------------------------
// K1: partial queries (blocks 0..255) + task planner (block 256).
// ---------------------------------------------------------------------------
__global__ void __launch_bounds__(128) queries_plan_kernel(
    const float* __restrict__ source, const float* __restrict__ Wmi,
    const float* __restrict__ Wpi, const int* __restrict__ lens,
    float* __restrict__ qpm, float* __restrict__ qpp,
    int* __restrict__ table)
{
    if (blockIdx.x == NB * 4) {
        if (threadIdx.x < 64) {
            const int lane = threadIdx.x;
            const int nc = (lens[lane] + LC - 1) >> 6;   // >=1
            int pre = nc;
            #pragma unroll
            for (int off = 1; off < 64; off <<= 1) {
                const int v = __shfl_up(pre, off);
                if (lane >= off) pre += v;
            }
            const int start = pre - nc;
            for (int j = 0; j < nc; ++j) table[start + j] = (lane << 6) | j;
            const int T = __shfl(pre, 63);
            for (int s = T + lane; s < NSLOT; s += 64) table[s] = -1;
        }
        return;
    }

    __shared__ float s[128];
    const int b  = blockIdx.x >> 2;
    const int eq = blockIdx.x & 3;
    const int t  = threadIdx.x;
    const int e0 = eq * 128;
    s[t] = source[b * ND + e0 + t];
    __syncthreads();

    const int d0 = t * 4;
    float4 a0 = {0,0,0,0}, a1 = {0,0,0,0};
    #pragma unroll 4
    for (int e = 0; e < 128; e += 2) {
        const float4 w0 = *(const float4*)(Wmi + (size_t)(e0 + e) * ND + d0);
        const float4 w1 = *(const float4*)(Wmi + (size_t)(e0 + e + 1) * ND + d0);
        const float x0 = s[e], x1 = s[e + 1];
        a0.x = fmaf(x0, w0.x, a0.x); a0.y = fmaf(x0, w0.y, a0.y);
        a0.z = fmaf(x0, w0.z, a0.z); a0.w = fmaf(x0, w0.w, a0.w);
        a1.x = fmaf(x1, w1.x, a1.x); a1.y = fmaf(x1, w1.y, a1.y);
        a1.z = fmaf(x1, w1.z, a1.z); a1.w = fmaf(x1, w1.w, a1.w);
    }
    a0.x += a1.x; a0.y += a1.y; a0.z += a1.z; a0.w += a1.w;
    *(float4*)(qpm + (size_t)(b * 4 + eq) * ND + d0) = a0;

    if (t < NDP) {
        float c0 = 0.f, c1 = 0.f;
        #pragma unroll 4
        for (int e = 0; e < 128; e += 2) {
            c0 = fmaf(s[e],     Wpi[(size_t)(e0 + e) * NDP + t],     c0);
            c1 = fmaf(s[e + 1], Wpi[(size_t)(e0 + e + 1) * NDP + t], c1);
        }
        qpp[(b * 4 + eq) * NDP + t] = c0 + c1;
    }
}

// ---------------------------------------------------------------------------
// K2: fused scorer, table-driven, copy-free ping-pong 4-row groups.
// While group A is processed, group B's 4 rows (9 KB/wave) are in flight:
// counted vmcnt waits, no register shifts, no per-row drains.
// ---------------------------------------------------------------------------
__global__ void __launch_bounds__(256, 4) pass1_kernel(
    const float* __restrict__ me, const float* __restrict__ pe,
    const float* __restrict__ qpm, const float* __restrict__ qpp,
    const int* __restrict__ mem_len, const int* __restrict__ table,
    float* __restrict__ a_main, float* __restrict__ a_pos,
    float* __restrict__ Sbuf, float* __restrict__ MZ)
{
    __shared__ __align__(16) float qp_lds[4][NDP];
    const int lane = threadIdx.x & 63;
    const int wid  = threadIdx.x >> 6;
    const int task = table[blockIdx.x * 4 + wid];
    if (task < 0) return;
    const int b  = task >> 6;
    const int lc = task & 63;

    const int len  = mem_len[b];
    const int l0   = lc * LC;
    const int nrow = min(LC, len - l0);
    const int nr4  = (nrow + 3) & ~3;
    const int last = nrow - 1;

    // query fragments (lane-distributed) + qp into LDS
    float4 q0 = {0,0,0,0}, q1 = {0,0,0,0};
    float qp = 0.f;
    #pragma unroll
    for (int eq = 0; eq < 4; ++eq) {
        const float4* qr = (const float4*)(qpm + (size_t)(b * 4 + eq) * ND);
        const float4 u0 = qr[lane], u1 = qr[64 + lane];
        q0.x += u0.x; q0.y += u0.y; q0.z += u0.z; q0.w += u0.w;
        q1.x += u1.x; q1.y += u1.y; q1.z += u1.z; q1.w += u1.w;
        qp += qpp[(b * 4 + eq) * NDP + lane];
    }
    qp_lds[wid][lane] = qp;

    // pe: lane j computes the full 64-dot for row l0+(j&31)
    float accp = 0.f;
    {
        const int prow = l0 + (lane & 31) ? l0 + (lane & 63) : l0;  // see below
    }
    // (lane handles row l0+lane when lane < nrow; others clamp harmlessly)
    {
        const int prow = l0 + min(lane, last);
        const float4* pr = (const float4*)(pe + ((size_t)prow * NB + b) * NDP);
        #pragma unroll
        for (int k = 0; k < 16; ++k) {
            const float4 pv = pr[k];
            const float4 qv = *(const float4*)&qp_lds[wid][k * 4];
            accp = fmaf(pv.x, qv.x, accp);
            accp = fmaf(pv.y, qv.y, accp);
            accp = fmaf(pv.z, qv.z, accp);
            accp = fmaf(pv.w, qv.w, accp);
        }
        if (lane < nrow) a_pos[(size_t)b * NL + l0 + lane] = accp;
    }
    const int accp_i = __float_as_int(accp);

    const size_t rstride = (size_t)NB * ND;
    const float* base = me + ((size_t)l0 * NB + b) * ND;

    float m = -1e30f, Z = 0.f, keep = 0.f;
    v2f S0 = {0,0}, S1 = {0,0}, S2 = {0,0}, S3 = {0,0};

    float4 A[4][2], B[4][2];

    // process one 4-row group (fully unrolled; interleaved butterflies)
    auto process = [&](float4 R[4][2], int i0) {
        float acc[4];
        #pragma unroll
        for (int j = 0; j < 4; ++j) {
            v2f dd = {0.f, 0.f};
            dd = fma2((v2f){R[j][0].x, R[j][0].y}, (v2f){q0.x, q0.y}, dd);
            dd = fma2((v2f){R[j][0].z, R[j][0].w}, (v2f){q0.z, q0.w}, dd);
            dd = fma2((v2f){R[j][1].x, R[j][1].y}, (v2f){q1.x, q1.y}, dd);
            dd = fma2((v2f){R[j][1].z, R[j][1].w}, (v2f){q1.z, q1.w}, dd);
            acc[j] = dd.x + dd.y;
        }
        #pragma unroll
        for (int off = 32; off; off >>= 1) {
            #pragma unroll
            for (int j = 0; j < 4; ++j)
                acc[j] += __shfl_xor(acc[j], off);
        }
        #pragma unroll
        for (int j = 0; j < 4; ++j) {
            const int row = i0 + j;
            keep = (lane == row) ? acc[j] : keep;
            const float ap = __int_as_float(
                __builtin_amdgcn_readlane(accp_i, min(row, last)));
            const float sv = (row < nrow) ? acc[j] + ap : -1e30f;
            if (sv > m) {                 // wave-uniform; new-max path w = 1
                const float sc = __expf(m - sv);
                const v2f sc2 = {sc, sc};
                Z = fmaf(Z, sc, 1.f);
                S0 = fma2(S0, sc2, (v2f){R[j][0].x, R[j][0].y});
                S1 = fma2(S1, sc2, (v2f){R[j][0].z, R[j][0].w});
                S2 = fma2(S2, sc2, (v2f){R[j][1].x, R[j][1].y});
                S3 = fma2(S3, sc2, (v2f){R[j][1].z, R[j][1].w});
                m = sv;
            } else {
                const float w = __expf(sv - m);
                const v2f w2 = {w, w};
                Z += w;
                S0 = fma2((v2f){R[j][0].x, R[j][0].y}, w2, S0);
                S1 = fma2((v2f){R[j][0].z, R[j][0].w}, w2, S1);
                S2 = fma2((v2f){R[j][1].x, R[j][1].y}, w2, S2);
                S3 = fma2((v2f){R[j][1].z, R[j][1].w}, w2, S3);
            }
        }
    };

    // prologue: A = rows 0..3 (clamped)
    #pragma unroll
    for (int j = 0; j < 4; ++j) {
        const float* p = base + (size_t)min(j, last) * rstride;
        A[j][0] = ((const float4*)p)[lane];
        A[j][1] = ((const float4*)p)[64 + lane];
    }

    int i = 0;
    for (;;) {
        #pragma unroll
        for (int j = 0; j < 4; ++j) {
            const float* p = base + (size_t)min(i + 4 + j, last) * rstride;
            B[j][0] = ((const float4*)p)[lane];
            B[j][1] = ((const float4*)p)[64 + lane];
        }
        process(A, i);
        i += 4;
        if (i >= nr4) break;

        #pragma unroll
        for (int j = 0; j < 4; ++j) {
            const float* p = base + (size_t)min(i + 4 + j, last) * rstride;
            A[j][0] = ((const float4*)p)[lane];
            A[j][1] = ((const float4*)p)[64 + lane];
        }
        process(B, i);
        i += 4;
        if (i >= nr4) break;
    }

    if (lane < nrow) a_main[(size_t)b * NL + l0 + lane] = keep;

    float* sp = Sbuf + ((size_t)b * NLC + lc) * ND;
    ((float4*)sp)[lane]      = (float4){S0.x, S0.y, S1.x, S1.y};
    ((float4*)sp)[64 + lane] = (float4){S2.x, S2.y, S3.x, S3.y};
    if (lane == 0) {
        MZ[2 * (b * NLC + lc)]     = m;
        MZ[2 * (b * NLC + lc) + 1] = Z;
    }
}

// ---------------------------------------------------------------------------
// K3 (merged): per-b stats + finalize + context sum. coef kept in LDS.
// ---------------------------------------------------------------------------
__global__ void __launch_bounds__(1024) stats_ctx_kernel(
    const float* __restrict__ MZ, const float* __restrict__ Sbuf,
    const int* __restrict__ mem_len,
    float* __restrict__ ma_io, float* __restrict__ pa_io,
    float* __restrict__ out_av, float* __restrict__ c_t)
{
    __shared__ float red[16][6];
    __shared__ float bc[6];
    __shared__ float coef_s[NLC];
    const int b = blockIdx.x;
    const int tid = threadIdx.x;
    const int lane = tid & 63, wid = tid >> 6;
    const int len = mem_len[b];

    float va[4], vp[4];
    float Am = -1e30f, Pm = -1e30f, Cm = -1e30f;
    #pragma unroll
    for (int k = 0; k < 4; ++k) {
        const int l = tid + k * 1024;
        va[k] = ma_io[(size_t)b * NL + l];
        vp[k] = pa_io[(size_t)b * NL + l];
        if (l < len) {
            Am = fmaxf(Am, va[k]);
            Pm = fmaxf(Pm, vp[k]);
            Cm = fmaxf(Cm, va[k] + vp[k]);
        }
    }
    #pragma unroll
    for (int off = 32; off; off >>= 1) {
        Am = fmaxf(Am, __shfl_xor(Am, off));
        Pm = fmaxf(Pm, __shfl_xor(Pm, off));
        Cm = fmaxf(Cm, __shfl_xor(Cm, off));
    }
    if (lane == 0) { red[wid][0] = Am; red[wid][1] = Pm; red[wid][2] = Cm; }
    __syncthreads();
    if (tid < 16) {
        float a = red[tid][0], p = red[tid][1], c = red[tid][2];
        #pragma unroll
        for (int off = 8; off; off >>= 1) {
            a = fmaxf(a, __shfl_xor(a, off));
            p = fmaxf(p, __shfl_xor(p, off));
            c = fmaxf(c, __shfl_xor(c, off));
        }
        if (tid == 0) { bc[0] = a; bc[1] = p; bc[2] = c; }
    }
    __syncthreads();
    const float MA = bc[0], MP = bc[1], MC = bc[2];

    float Az = 0.f, Pz = 0.f, Cz = 0.f;
    #pragma unroll
    for (int k = 0; k < 4; ++k) {
        const int l = tid + k * 1024;
        if (l < len) {
            Az += __expf(va[k] - MA);
            Pz += __expf(vp[k] - MP);
            Cz += __expf(va[k] + vp[k] - MC);
        }
    }
    #pragma unroll
    for (int off = 32; off; off >>= 1) {
        Az += __shfl_xor(Az, off);
        Pz += __shfl_xor(Pz, off);
        Cz += __shfl_xor(Cz, off);
    }
    if (lane == 0) { red[wid][3] = Az; red[wid][4] = Pz; red[wid][5] = Cz; }
    __syncthreads();
    if (tid < 16) {
        float a = red[tid][3], p = red[tid][4], c = red[tid][5];
        #pragma unroll
        for (int off = 8; off; off >>= 1) {
            a += __shfl_xor(a, off);
            p += __shfl_xor(p, off);
            c += __shfl_xor(c, off);
        }
        if (tid == 0) { bc[3] = a; bc[4] = p; bc[5] = c; }
    }
    __syncthreads();
    const float iA = 1.f / bc[3], iP = 1.f / bc[4], iC = 1.f / bc[5];
    const int nv = (len + LC - 1) >> 6;

    if (tid < NLC) {
        const float mlc = MZ[2 * (b * NLC + tid)];
        coef_s[tid] = (tid < nv) ? __expf(mlc - MC) * iC : 0.f;
    }

    #pragma unroll
    for (int k = 0; k < 4; ++k) {
        const int l = tid + k * 1024;
        const bool v = l < len;
        const size_t idx = (size_t)b * NL + l;
        ma_io[idx]  = v ? __expf(va[k] - MA) * iA : 0.f;
        pa_io[idx]  = v ? __expf(vp[k] - MP) * iP : 0.f;
        out_av[idx] = v ? __expf(va[k] + vp[k] - MC) * iC : 0.f;
    }
    __syncthreads();

    // context sum: 128 threads x float4 over valid chunks
    if (tid < 128) {
        float4 acc = {0.f, 0.f, 0.f, 0.f};
        for (int lcc = 0; lcc < nv; ++lcc) {
            const float cf = coef_s[lcc];
            const float4 sv4 =
                ((const float4*)(Sbuf + ((size_t)b * NLC + lcc) * ND))[tid];
            acc.x = fmaf(cf, sv4.x, acc.x);
            acc.y = fmaf(cf, sv4.y, acc.y);
            acc.z = fmaf(cf, sv4.z, acc.z);
            acc.w = fmaf(cf, sv4.w, acc.w);
        }
        ((float4*)(c_t + b * ND))[tid] = acc;
    }
}

// ---------------------------------------------------------------------------
// K4: attn_h[b,e] = tanh(<[c_t, source], W_out[e,:]>)
// ---------------------------------------------------------------------------
__global__ void __launch_bounds__(256) out_kernel(
    const float* __restrict__ c_t, const float* __restrict__ source,
    const float* __restrict__ Wout, float* __restrict__ attn_h)
{
    __shared__ float cs[2 * ND];
    const int b = blockIdx.x >> 3;
    const int eg = blockIdx.x & 7;
    const int tid = threadIdx.x;

    for (int d = tid; d < ND; d += 256) {
        cs[d] = c_t[b * ND + d];
        cs[ND + d] = source[b * ND + d];
    }
    __syncthreads();

    const int wid = tid >> 6, lane = tid & 63;
    const float4* csv = (const float4*)cs;
    for (int e = eg * 64 + wid; e < eg * 64 + 64; e += 4) {
        const float4* wrow = (const float4*)(Wout + (size_t)e * 2 * ND);
        float acc = 0.f;
        #pragma unroll
        for (int j = 0; j < 4; ++j) {
            const float4 w = wrow[lane + 64 * j];
            const float4 c = csv[lane + 64 * j];
            acc += w.x * c.x + w.y * c.y + w.z * c.z + w.w * c.w;
        }
        #pragma unroll
        for (int off = 32; off; off >>= 1) acc += __shfl_xor(acc, off);
        if (lane == 0) attn_h[(size_t)b * ND + e] = tanhf(acc);
    }
}

// ---------------------------------------------------------------------------
extern "C" void kernel_launch(void* const* d_in, const int* in_sizes, int n_in,
                              void* d_out, int out_size, void* d_ws, size_t ws_size,
                              hipStream_t stream)
{
    const float* source = (const float*)d_in[0];
    const float* me     = (const float*)d_in[1];   // (L, B, D)
    const float* pe     = (const float*)d_in[2];   // (L, B, DP)
    const float* Wmi    = (const float*)d_in[3];   // (D, D)
    const float* Wpi    = (const float*)d_in[4];   // (D, DP)
    const float* Wout   = (const float*)d_in[5];   // (D, 2D)
    const int*   lens   = (const int*)d_in[6];     // (B,)

    float* out    = (float*)d_out;
    float* attn_h = out;                     // (B, D)
    float* av     = attn_h + NB * ND;        // (B, L)
    float* ma     = av + NB * NL;            // (B, L) raw a_main -> in-place
    float* pa     = ma + NB * NL;            // (B, L) raw a_pos  -> in-place

    float* ws    = (float*)d_ws;
    float* qpm   = ws;                              // NB*4*ND
    float* qpp   = qpm + NB * 4 * ND;               // NB*4*NDP
    float* Sbuf  = qpp + NB * 4 * NDP;              // NB*NLC*ND
    float* MZ    = Sbuf + (size_t)NB * NLC * ND;    // NB*NLC*2
    float* c_t   = MZ + NB * NLC * 2;               // NB*ND
    int*   table = (int*)(c_t + NB * ND);           // NSLOT ints

    queries_plan_kernel<<<NB * 4 + 1, 128, 0, stream>>>(source, Wmi, Wpi,
                                                        lens, qpm, qpp, table);
    pass1_kernel       <<<NSLOT / 4, 256, 0, stream>>>(me, pe, qpm, qpp, lens,
                                                       table, ma, pa, Sbuf, MZ);
    stats_ctx_kernel   <<<NB, 1024, 0, stream>>>(MZ, Sbuf, lens, ma, pa, av, c_t);
    out_kernel         <<<NB * 8, 256, 0, stream>>>(c_t, source, Wout, attn_h);
}

// Round 12
// 114.052 us; speedup vs baseline: 1.0108x; 1.0097x over previous
//
#include <hip/hip_runtime.h>
#include <cstddef>

#define NB 64
#define NL 4096
#define ND 512
#define NDP 64
#define LC 64
#define NLC (NL / LC)    // 64
#define NSLOT 4096       // wave slots in pass1 (1024 blocks x 4 waves)

typedef float v2f __attribute__((ext_vector_type(2)));

__device__ __forceinline__ v2f fma2(v2f a, v2f b, v2f c) {
    return __builtin_elementwise_fma(a, b, c);
}

// ---------------------------------------------------------------------------
// K1: partial queries (blocks 0..255) + task planner (block 256).
// Planner builds the task table LC-MAJOR, B-MINOR: slot order = (lc, b) so a
// pass1 block's 4 waves own 4 CONSECUTIVE b columns at the same l-range ->
// 8 KB contiguous DRAM bursts instead of isolated 2 KB islands.
// NOTE: group offsets go through LDS (exec-independent); __shfl from a lane
// that exited a divergent loop is undefined (ds_bpermute honors EXEC).
// ---------------------------------------------------------------------------
__global__ void __launch_bounds__(128) queries_plan_kernel(
    const float* __restrict__ source, const float* __restrict__ Wmi,
    const float* __restrict__ Wpi, const int* __restrict__ lens,
    float* __restrict__ qpm, float* __restrict__ qpp,
    int* __restrict__ table)
{
    if (blockIdx.x == NB * 4) {
        __shared__ unsigned long long masks[64];
        __shared__ int excl_lds[64];
        const int tid = threadIdx.x;
        if (tid < 64) {
            const int lane = tid;                       // lane = b
            const int nc = (lens[lane] + LC - 1) >> 6;  // chunks for b (>=1)
            // masks[lc] = bitmask of b's having a task at this lc
            for (int lc = 0; lc < 64; ++lc) {
                const unsigned long long m = __ballot(nc > lc);
                if (lane == lc) masks[lc] = m;
            }
            const int cnt = __popcll(masks[lane]);      // tasks at lc=lane
            int incl = cnt;                             // inclusive scan
            #pragma unroll
            for (int off = 1; off < 64; off <<= 1) {
                const int v = __shfl_up(incl, off);
                if (lane >= off) incl += v;
            }
            excl_lds[lane] = incl - cnt;                // group offset of lc=lane
            const int T = __shfl(incl, 63);             // converged: all active
            const unsigned long long below = ((1ull << lane) - 1ull);
            for (int j = 0; j < nc; ++j) {              // divergent is now safe:
                const int excl = excl_lds[j];           // LDS read, not shfl
                const int rank = __popcll(masks[j] & below);
                table[excl + rank] = (lane << 6) | j;   // (b<<6)|lc
            }
            for (int s = T + lane; s < NSLOT; s += 64) table[s] = -1;
        }
        return;
    }

    __shared__ float s[128];
    const int b  = blockIdx.x >> 2;
    const int eq = blockIdx.x & 3;
    const int t  = threadIdx.x;
    const int e0 = eq * 128;
    s[t] = source[b * ND + e0 + t];
    __syncthreads();

    const int d0 = t * 4;
    float4 a0 = {0,0,0,0}, a1 = {0,0,0,0};
    #pragma unroll 4
    for (int e = 0; e < 128; e += 2) {
        const float4 w0 = *(const float4*)(Wmi + (size_t)(e0 + e) * ND + d0);
        const float4 w1 = *(const float4*)(Wmi + (size_t)(e0 + e + 1) * ND + d0);
        const float x0 = s[e], x1 = s[e + 1];
        a0.x = fmaf(x0, w0.x, a0.x); a0.y = fmaf(x0, w0.y, a0.y);
        a0.z = fmaf(x0, w0.z, a0.z); a0.w = fmaf(x0, w0.w, a0.w);
        a1.x = fmaf(x1, w1.x, a1.x); a1.y = fmaf(x1, w1.y, a1.y);
        a1.z = fmaf(x1, w1.z, a1.z); a1.w = fmaf(x1, w1.w, a1.w);
    }
    a0.x += a1.x; a0.y += a1.y; a0.z += a1.z; a0.w += a1.w;
    *(float4*)(qpm + (size_t)(b * 4 + eq) * ND + d0) = a0;

    if (t < NDP) {
        float c0 = 0.f, c1 = 0.f;
        #pragma unroll 4
        for (int e = 0; e < 128; e += 2) {
            c0 = fmaf(s[e],     Wpi[(size_t)(e0 + e) * NDP + t],     c0);
            c1 = fmaf(s[e + 1], Wpi[(size_t)(e0 + e + 1) * NDP + t], c1);
        }
        qpp[(b * 4 + eq) * NDP + t] = c0 + c1;
    }
}

// ---------------------------------------------------------------------------
// K2: fused scorer, table-driven (lc-major table -> consecutive-b waves per
// block), copy-free ping-pong 4-row groups (9 KB/wave in flight).
// ---------------------------------------------------------------------------
__global__ void __launch_bounds__(256, 4) pass1_kernel(
    const float* __restrict__ me, const float* __restrict__ pe,
    const float* __restrict__ qpm, const float* __restrict__ qpp,
    const int* __restrict__ mem_len, const int* __restrict__ table,
    float* __restrict__ a_main, float* __restrict__ a_pos,
    float* __restrict__ Sbuf, float* __restrict__ MZ)
{
    __shared__ __align__(16) float qp_lds[4][NDP];
    const int lane = threadIdx.x & 63;
    const int wid  = threadIdx.x >> 6;
    const int task = table[blockIdx.x * 4 + wid];
    if (task < 0) return;
    const int b  = task >> 6;
    const int lc = task & 63;

    const int len  = mem_len[b];
    const int l0   = lc * LC;
    const int nrow = min(LC, len - l0);
    const int nr4  = (nrow + 3) & ~3;
    const int last = nrow - 1;

    // query fragments (lane-distributed) + qp into LDS
    float4 q0 = {0,0,0,0}, q1 = {0,0,0,0};
    float qp = 0.f;
    #pragma unroll
    for (int eq = 0; eq < 4; ++eq) {
        const float4* qr = (const float4*)(qpm + (size_t)(b * 4 + eq) * ND);
        const float4 u0 = qr[lane], u1 = qr[64 + lane];
        q0.x += u0.x; q0.y += u0.y; q0.z += u0.z; q0.w += u0.w;
        q1.x += u1.x; q1.y += u1.y; q1.z += u1.z; q1.w += u1.w;
        qp += qpp[(b * 4 + eq) * NDP + lane];
    }
    qp_lds[wid][lane] = qp;

    // pe: lane j computes the full 64-dot for row l0+j (qp broadcast via LDS)
    float accp = 0.f;
    {
        const int prow = l0 + min(lane, last);
        const float4* pr = (const float4*)(pe + ((size_t)prow * NB + b) * NDP);
        #pragma unroll
        for (int k = 0; k < 16; ++k) {
            const float4 pv = pr[k];
            const float4 qv = *(const float4*)&qp_lds[wid][k * 4];
            accp = fmaf(pv.x, qv.x, accp);
            accp = fmaf(pv.y, qv.y, accp);
            accp = fmaf(pv.z, qv.z, accp);
            accp = fmaf(pv.w, qv.w, accp);
        }
        if (lane < nrow) a_pos[(size_t)b * NL + l0 + lane] = accp;
    }
    const int accp_i = __float_as_int(accp);

    const size_t rstride = (size_t)NB * ND;
    const float* base = me + ((size_t)l0 * NB + b) * ND;

    float m = -1e30f, Z = 0.f, keep = 0.f;
    v2f S0 = {0,0}, S1 = {0,0}, S2 = {0,0}, S3 = {0,0};

    float4 A[4][2], B[4][2];

    auto process = [&](float4 R[4][2], int i0) {
        float acc[4];
        #pragma unroll
        for (int j = 0; j < 4; ++j) {
            v2f dd = {0.f, 0.f};
            dd = fma2((v2f){R[j][0].x, R[j][0].y}, (v2f){q0.x, q0.y}, dd);
            dd = fma2((v2f){R[j][0].z, R[j][0].w}, (v2f){q0.z, q0.w}, dd);
            dd = fma2((v2f){R[j][1].x, R[j][1].y}, (v2f){q1.x, q1.y}, dd);
            dd = fma2((v2f){R[j][1].z, R[j][1].w}, (v2f){q1.z, q1.w}, dd);
            acc[j] = dd.x + dd.y;
        }
        #pragma unroll
        for (int off = 32; off; off >>= 1) {
            #pragma unroll
            for (int j = 0; j < 4; ++j)
                acc[j] += __shfl_xor(acc[j], off);
        }
        #pragma unroll
        for (int j = 0; j < 4; ++j) {
            const int row = i0 + j;
            keep = (lane == row) ? acc[j] : keep;
            const float ap = __int_as_float(
                __builtin_amdgcn_readlane(accp_i, min(row, last)));
            const float sv = (row < nrow) ? acc[j] + ap : -1e30f;
            if (sv > m) {                 // wave-uniform; new-max path w = 1
                const float sc = __expf(m - sv);
                const v2f sc2 = {sc, sc};
                Z = fmaf(Z, sc, 1.f);
                S0 = fma2(S0, sc2, (v2f){R[j][0].x, R[j][0].y});
                S1 = fma2(S1, sc2, (v2f){R[j][0].z, R[j][0].w});
                S2 = fma2(S2, sc2, (v2f){R[j][1].x, R[j][1].y});
                S3 = fma2(S3, sc2, (v2f){R[j][1].z, R[j][1].w});
                m = sv;
            } else {
                const float w = __expf(sv - m);
                const v2f w2 = {w, w};
                Z += w;
                S0 = fma2((v2f){R[j][0].x, R[j][0].y}, w2, S0);
                S1 = fma2((v2f){R[j][0].z, R[j][0].w}, w2, S1);
                S2 = fma2((v2f){R[j][1].x, R[j][1].y}, w2, S2);
                S3 = fma2((v2f){R[j][1].z, R[j][1].w}, w2, S3);
            }
        }
    };

    #pragma unroll
    for (int j = 0; j < 4; ++j) {
        const float* p = base + (size_t)min(j, last) * rstride;
        A[j][0] = ((const float4*)p)[lane];
        A[j][1] = ((const float4*)p)[64 + lane];
    }

    int i = 0;
    for (;;) {
        #pragma unroll
        for (int j = 0; j < 4; ++j) {
            const float* p = base + (size_t)min(i + 4 + j, last) * rstride;
            B[j][0] = ((const float4*)p)[lane];
            B[j][1] = ((const float4*)p)[64 + lane];
        }
        process(A, i);
        i += 4;
        if (i >= nr4) break;

        #pragma unroll
        for (int j = 0; j < 4; ++j) {
            const float* p = base + (size_t)min(i + 4 + j, last) * rstride;
            A[j][0] = ((const float4*)p)[lane];
            A[j][1] = ((const float4*)p)[64 + lane];
        }
        process(B, i);
        i += 4;
        if (i >= nr4) break;
    }

    if (lane < nrow) a_main[(size_t)b * NL + l0 + lane] = keep;

    float* sp = Sbuf + ((size_t)b * NLC + lc) * ND;
    ((float4*)sp)[lane]      = (float4){S0.x, S0.y, S1.x, S1.y};
    ((float4*)sp)[64 + lane] = (float4){S2.x, S2.y, S3.x, S3.y};
    if (lane == 0) {
        MZ[2 * (b * NLC + lc)]     = m;
        MZ[2 * (b * NLC + lc) + 1] = Z;
    }
}

// ---------------------------------------------------------------------------
// K3 (fully merged tail): per-b stats + finalize + context sum + output
// projection. c_t lives in LDS; one launch instead of two.
// ---------------------------------------------------------------------------
__global__ void __launch_bounds__(1024) tail_kernel(
    const float* __restrict__ MZ, const float* __restrict__ Sbuf,
    const int* __restrict__ mem_len, const float* __restrict__ source,
    const float* __restrict__ Wout,
    float* __restrict__ ma_io, float* __restrict__ pa_io,
    float* __restrict__ out_av, float* __restrict__ attn_h)
{
    __shared__ float red[16][6];
    __shared__ float bc[6];
    __shared__ float coef_s[NLC];
    __shared__ __align__(16) float cs[2 * ND];   // [c_t | source]
    const int b = blockIdx.x;
    const int tid = threadIdx.x;
    const int lane = tid & 63, wid = tid >> 6;
    const int len = mem_len[b];

    float va[4], vp[4];
    float Am = -1e30f, Pm = -1e30f, Cm = -1e30f;
    #pragma unroll
    for (int k = 0; k < 4; ++k) {
        const int l = tid + k * 1024;
        va[k] = ma_io[(size_t)b * NL + l];
        vp[k] = pa_io[(size_t)b * NL + l];
        if (l < len) {
            Am = fmaxf(Am, va[k]);
            Pm = fmaxf(Pm, vp[k]);
            Cm = fmaxf(Cm, va[k] + vp[k]);
        }
    }
    #pragma unroll
    for (int off = 32; off; off >>= 1) {
        Am = fmaxf(Am, __shfl_xor(Am, off));
        Pm = fmaxf(Pm, __shfl_xor(Pm, off));
        Cm = fmaxf(Cm, __shfl_xor(Cm, off));
    }
    if (lane == 0) { red[wid][0] = Am; red[wid][1] = Pm; red[wid][2] = Cm; }
    __syncthreads();
    if (tid < 16) {
        float a = red[tid][0], p = red[tid][1], c = red[tid][2];
        #pragma unroll
        for (int off = 8; off; off >>= 1) {
            a = fmaxf(a, __shfl_xor(a, off));
            p = fmaxf(p, __shfl_xor(p, off));
            c = fmaxf(c, __shfl_xor(c, off));
        }
        if (tid == 0) { bc[0] = a; bc[1] = p; bc[2] = c; }
    }
    __syncthreads();
    const float MA = bc[0], MP = bc[1], MC = bc[2];

    float Az = 0.f, Pz = 0.f, Cz = 0.f;
    #pragma unroll
    for (int k = 0; k < 4; ++k) {
        const int l = tid + k * 1024;
        if (l < len) {
            Az += __expf(va[k] - MA);
            Pz += __expf(vp[k] - MP);
            Cz += __expf(va[k] + vp[k] - MC);
        }
    }
    #pragma unroll
    for (int off = 32; off; off >>= 1) {
        Az += __shfl_xor(Az, off);
        Pz += __shfl_xor(Pz, off);
        Cz += __shfl_xor(Cz, off);
    }
    if (lane == 0) { red[wid][3] = Az; red[wid][4] = Pz; red[wid][5] = Cz; }
    __syncthreads();
    if (tid < 16) {
        float a = red[tid][3], p = red[tid][4], c = red[tid][5];
        #pragma unroll
        for (int off = 8; off; off >>= 1) {
            a += __shfl_xor(a, off);
            p += __shfl_xor(p, off);
            c += __shfl_xor(c, off);
        }
        if (tid == 0) { bc[3] = a; bc[4] = p; bc[5] = c; }
    }
    __syncthreads();
    const float iA = 1.f / bc[3], iP = 1.f / bc[4], iC = 1.f / bc[5];
    const int nv = (len + LC - 1) >> 6;

    if (tid < NLC) {
        const float mlc = MZ[2 * (b * NLC + tid)];
        coef_s[tid] = (tid < nv) ? __expf(mlc - MC) * iC : 0.f;
    }
    if (tid >= 512) cs[ND + (tid - 512)] = source[b * ND + (tid - 512)];

    #pragma unroll
    for (int k = 0; k < 4; ++k) {
        const int l = tid + k * 1024;
        const bool v = l < len;
        const size_t idx = (size_t)b * NL + l;
        ma_io[idx]  = v ? __expf(va[k] - MA) * iA : 0.f;
        pa_io[idx]  = v ? __expf(vp[k] - MP) * iP : 0.f;
        out_av[idx] = v ? __expf(va[k] + vp[k] - MC) * iC : 0.f;
    }
    __syncthreads();

    // context sum into LDS: 128 threads x float4 over valid chunks
    if (tid < 128) {
        float4 acc = {0.f, 0.f, 0.f, 0.f};
        for (int lcc = 0; lcc < nv; ++lcc) {
            const float cf = coef_s[lcc];
            const float4 sv4 =
                ((const float4*)(Sbuf + ((size_t)b * NLC + lcc) * ND))[tid];
            acc.x = fmaf(cf, sv4.x, acc.x);
            acc.y = fmaf(cf, sv4.y, acc.y);
            acc.z = fmaf(cf, sv4.z, acc.z);
            acc.w = fmaf(cf, sv4.w, acc.w);
        }
        ((float4*)cs)[tid] = acc;
    }
    __syncthreads();

    // output projection: wave per row, coalesced Wout reads
    const float4* csv = (const float4*)cs;
    for (int e = wid; e < ND; e += 16) {
        const float4* wrow = (const float4*)(Wout + (size_t)e * 2 * ND);
        float acc = 0.f;
        #pragma unroll
        for (int j = 0; j < 4; ++j) {
            const float4 w = wrow[lane + 64 * j];
            const float4 c = csv[lane + 64 * j];
            acc += w.x * c.x + w.y * c.y + w.z * c.z + w.w * c.w;
        }
        #pragma unroll
        for (int off = 32; off; off >>= 1) acc += __shfl_xor(acc, off);
        if (lane == 0) attn_h[(size_t)b * ND + e] = tanhf(acc);
    }
}

// ---------------------------------------------------------------------------
extern "C" void kernel_launch(void* const* d_in, const int* in_sizes, int n_in,
                              void* d_out, int out_size, void* d_ws, size_t ws_size,
                              hipStream_t stream)
{
    const float* source = (const float*)d_in[0];
    const float* me     = (const float*)d_in[1];   // (L, B, D)
    const float* pe     = (const float*)d_in[2];   // (L, B, DP)
    const float* Wmi    = (const float*)d_in[3];   // (D, D)
    const float* Wpi    = (const float*)d_in[4];   // (D, DP)
    const float* Wout   = (const float*)d_in[5];   // (D, 2D)
    const int*   lens   = (const int*)d_in[6];     // (B,)

    float* out    = (float*)d_out;
    float* attn_h = out;                     // (B, D)
    float* av     = attn_h + NB * ND;        // (B, L)
    float* ma     = av + NB * NL;            // (B, L) raw a_main -> in-place
    float* pa     = ma + NB * NL;            // (B, L) raw a_pos  -> in-place

    float* ws    = (float*)d_ws;
    float* qpm   = ws;                              // NB*4*ND
    float* qpp   = qpm + NB * 4 * ND;               // NB*4*NDP
    float* Sbuf  = qpp + NB * 4 * NDP;              // NB*NLC*ND
    float* MZ    = Sbuf + (size_t)NB * NLC * ND;    // NB*NLC*2
    int*   table = (int*)(MZ + NB * NLC * 2);       // NSLOT ints

    queries_plan_kernel<<<NB * 4 + 1, 128, 0, stream>>>(source, Wmi, Wpi,
                                                        lens, qpm, qpp, table);
    pass1_kernel       <<<NSLOT / 4, 256, 0, stream>>>(me, pe, qpm, qpp, lens,
                                                       table, ma, pa, Sbuf, MZ);
    tail_kernel        <<<NB, 1024, 0, stream>>>(MZ, Sbuf, lens, source, Wout,
                                                 ma, pa, av, attn_h);
}